// Round 1
// baseline (1564.888 us; speedup 1.0000x reference)
//
#include <hip/hip_runtime.h>
#include <math.h>

#define B_ 32
#define C_ 32
#define N_ 512
#define T_ 480
#define EPS_ 1e-5f

static constexpr int    BCT  = B_ * C_ * T_;             // 491520
static constexpr long   BTT  = (long)B_ * T_ * T_;       // 7372800

// ---------------------------------------------------------------------------
// Kernel A: one pass over seq (1 GB) computing
//   tmp[b,c,t] = sum_n (sum_c' seq[b,c',n,t]*w1[c']) * w[n,c]   (= f1 @ w, transposed store)
//   f2 [b,c,t] = sum_n seq[b,c,n,t]*w2[n]
// Layouts chosen [B,C,T] so the per-thread (one t each) atomics are lane-coalesced.
// Grid: (t-chunks=8, b=32, n-chunks=16), block=64 (one wave).
// ---------------------------------------------------------------------------
__global__ __launch_bounds__(64) void kA(const float* __restrict__ seq,
                                         const float* __restrict__ w1,
                                         const float* __restrict__ w2,
                                         const float* __restrict__ w,
                                         float* __restrict__ tmp,
                                         float* __restrict__ f2) {
    const int t  = blockIdx.x * 64 + threadIdx.x;
    const int b  = blockIdx.y;
    const int n0 = blockIdx.z * 32;
    if (t >= T_) return;

    float w1r[C_];
    #pragma unroll
    for (int c = 0; c < C_; ++c) w1r[c] = w1[c];   // uniform -> SGPRs

    float f2acc[C_] = {};
    float tmpacc[C_] = {};

    const float* base = seq + (size_t)b * C_ * N_ * T_ + t;
    for (int n = n0; n < n0 + 32; ++n) {
        const float w2n = w2[n];
        const float* p  = base + (size_t)n * T_;
        float s1 = 0.f;
        #pragma unroll
        for (int c = 0; c < C_; ++c) {
            float v = p[(size_t)c * N_ * T_];
            s1        += v * w1r[c];
            f2acc[c]  += v * w2n;
        }
        const float* wr = w + n * C_;   // uniform row -> scalar loads
        #pragma unroll
        for (int c = 0; c < C_; ++c) tmpacc[c] += s1 * wr[c];
    }

    #pragma unroll
    for (int c = 0; c < C_; ++c) {
        atomicAdd(&tmp[((size_t)b * C_ + c) * T_ + t], tmpacc[c]);
        atomicAdd(&f2 [((size_t)b * C_ + c) * T_ + t], f2acc[c]);
    }
}

// ---------------------------------------------------------------------------
// Kernel B: L[b,t,s] = sigmoid( sum_c tmp[b,c,t]*f2[b,c,s] + bias[t,s] )
// tmp reads are block-uniform (scalar); f2/bias coalesced on s.
// Grid: (2, T, B), block=256.
// ---------------------------------------------------------------------------
__global__ __launch_bounds__(256) void kB(const float* __restrict__ tmp,
                                          const float* __restrict__ f2,
                                          const float* __restrict__ bias,
                                          float* __restrict__ L) {
    const int s = blockIdx.x * 256 + threadIdx.x;
    const int t = blockIdx.y;
    const int b = blockIdx.z;
    if (s >= T_) return;
    float acc = bias[t * T_ + s];
    #pragma unroll
    for (int c = 0; c < C_; ++c)
        acc += tmp[((size_t)b * C_ + c) * T_ + t] * f2[((size_t)b * C_ + c) * T_ + s];
    const float sg = 1.f / (1.f + __expf(-acc));
    L[((size_t)b * T_ + t) * T_ + s] = sg;
}

// ---------------------------------------------------------------------------
// Kernel C: out[b,t,u] = sum_s v[t,s] * L[b,s,u]   (batched fp32 GEMM)
// 64x64 tile, BK=16, 256 threads, 4x4 micro-tile, LDS staging.
// Grid: (u-tiles=8, t-tiles=8, b=32).
// ---------------------------------------------------------------------------
__global__ __launch_bounds__(256) void kC(const float* __restrict__ v,
                                          const float* __restrict__ L,
                                          float* __restrict__ out) {
    __shared__ float Vs[16][68];   // [k][m], stride 68 keeps float4 reads aligned
    __shared__ float Ls[16][64];   // [k][n]

    const int b   = blockIdx.z;
    const int t0  = blockIdx.y * 64;
    const int u0  = blockIdx.x * 64;
    const int tid = threadIdx.x;
    const int tx  = tid & 15, ty = tid >> 4;

    float acc[4][4] = {};
    const float* Lb = L + (size_t)b * T_ * T_;

    for (int k0 = 0; k0 < T_; k0 += 16) {
        {   // stage v tile (transposed into Vs[k][m])
            const int i = tid >> 2, j4 = (tid & 3) * 4;
            float4 val = make_float4(0.f, 0.f, 0.f, 0.f);
            if (t0 + i < T_)
                val = *(const float4*)(v + (size_t)(t0 + i) * T_ + k0 + j4);
            Vs[j4 + 0][i] = val.x; Vs[j4 + 1][i] = val.y;
            Vs[j4 + 2][i] = val.z; Vs[j4 + 3][i] = val.w;
        }
        {   // stage L tile
            const int i = tid >> 4, j4 = (tid & 15) * 4;
            float4 val = make_float4(0.f, 0.f, 0.f, 0.f);
            if (u0 + j4 < T_)
                val = *(const float4*)(Lb + (size_t)(k0 + i) * T_ + u0 + j4);
            *(float4*)&Ls[i][j4] = val;
        }
        __syncthreads();
        #pragma unroll
        for (int kk = 0; kk < 16; ++kk) {
            float4 av = *(const float4*)&Vs[kk][ty * 4];
            float4 bv = *(const float4*)&Ls[kk][tx * 4];
            const float a0[4] = {av.x, av.y, av.z, av.w};
            const float b0[4] = {bv.x, bv.y, bv.z, bv.w};
            #pragma unroll
            for (int i = 0; i < 4; ++i)
                #pragma unroll
                for (int j = 0; j < 4; ++j)
                    acc[i][j] += a0[i] * b0[j];
        }
        __syncthreads();
    }

    #pragma unroll
    for (int i = 0; i < 4; ++i) {
        const int t = t0 + ty * 4 + i;
        const int u = u0 + tx * 4;
        if (t < T_ && u < T_)
            *(float4*)(out + ((size_t)b * T_ + t) * T_ + u) =
                make_float4(acc[i][0], acc[i][1], acc[i][2], acc[i][3]);
    }
}

// ---------------------------------------------------------------------------
// Kernel D: BN stats. sums[u] = sum over rows of L2[., u]; sums[T+u] = sumsq.
// Thread per column u, 240 rows per block, coalesced reads, 2 atomics/thread.
// Grid: 64, block=512 (480 active).
// ---------------------------------------------------------------------------
__global__ __launch_bounds__(512) void kD(const float* __restrict__ L2,
                                          float* __restrict__ sums) {
    const int u = threadIdx.x;
    if (u >= T_) return;
    const long r0 = (long)blockIdx.x * 240;
    float s = 0.f, q = 0.f;
    for (int i = 0; i < 240; ++i) {
        const float val = L2[(r0 + i) * T_ + u];
        s += val;
        q += val * val;
    }
    atomicAdd(&sums[u], s);
    atomicAdd(&sums[T_ + u], q);
}

// ---------------------------------------------------------------------------
// Kernel E: in-place BN-normalize + mask + row softmax. One wave per row.
// Grid: 3840, block=256 (4 waves -> 4 rows).
// ---------------------------------------------------------------------------
__global__ __launch_bounds__(256) void kE(float* __restrict__ L2,
                                          const float* __restrict__ sums,
                                          const float* __restrict__ gamma,
                                          const float* __restrict__ beta,
                                          const float* __restrict__ mask) {
    const int lane = threadIdx.x & 63;
    const int wid  = threadIdx.x >> 6;
    const long r   = (long)blockIdx.x * 4 + wid;   // 0..15359
    const int t    = (int)(r % T_);
    const float inv_cnt = 1.f / (float)(B_ * T_);

    float x[8];
    float m = -INFINITY;
    #pragma unroll
    for (int j = 0; j < 8; ++j) {
        const int u = lane + 64 * j;
        if (u < T_) {
            const float mean = sums[u] * inv_cnt;
            const float var  = sums[T_ + u] * inv_cnt - mean * mean;
            const float sc   = gamma[u] * rsqrtf(var + EPS_);
            const float val  = (L2[r * T_ + u] - mean) * sc + beta[u] + mask[t * T_ + u];
            x[j] = val;
            m = fmaxf(m, val);
        } else {
            x[j] = -INFINITY;
        }
    }
    #pragma unroll
    for (int off = 32; off >= 1; off >>= 1) m = fmaxf(m, __shfl_xor(m, off));

    float ssum = 0.f;
    #pragma unroll
    for (int j = 0; j < 8; ++j) {
        const float e = (x[j] == -INFINITY) ? 0.f : __expf(x[j] - m);
        x[j] = e;
        ssum += e;
    }
    #pragma unroll
    for (int off = 32; off >= 1; off >>= 1) ssum += __shfl_xor(ssum, off);

    const float inv = 1.f / ssum;
    #pragma unroll
    for (int j = 0; j < 8; ++j) {
        const int u = lane + 64 * j;
        if (u < T_) L2[r * T_ + u] = x[j] * inv;
    }
}

// ---------------------------------------------------------------------------
extern "C" void kernel_launch(void* const* d_in, const int* in_sizes, int n_in,
                              void* d_out, int out_size, void* d_ws, size_t ws_size,
                              hipStream_t stream) {
    const float* seq   = (const float*)d_in[0];
    const float* w1    = (const float*)d_in[1];
    const float* w2    = (const float*)d_in[2];
    const float* w     = (const float*)d_in[3];
    const float* bias  = (const float*)d_in[4];
    const float* v     = (const float*)d_in[5];
    const float* gamma = (const float*)d_in[6];
    const float* beta  = (const float*)d_in[7];
    const float* mask  = (const float*)d_in[8];
    float* out = (float*)d_out;
    float* ws  = (float*)d_ws;

    float* tmp  = ws;                       // [B,C,T]
    float* f2   = ws + BCT;                 // [B,C,T]
    float* sums = ws + 2 * BCT;             // [2*T]
    float* L    = ws + 2 * BCT + 2 * T_;    // [B,T,T] sigmoid logits

    // zero the atomic accumulators (ws is poisoned 0xAA before every launch)
    hipMemsetAsync(ws, 0, (size_t)(2 * BCT + 2 * T_) * sizeof(float), stream);

    kA<<<dim3(8, 32, 16), 64, 0, stream>>>(seq, w1, w2, w, tmp, f2);
    kB<<<dim3(2, T_, B_), 256, 0, stream>>>(tmp, f2, bias, L);
    kC<<<dim3(8, 8, B_), 256, 0, stream>>>(v, L, out);      // out = L2 (pre-BN)
    kD<<<64, 512, 0, stream>>>(out, sums);
    kE<<<3840, 256, 0, stream>>>(out, sums, gamma, beta, mask);
}